// Round 4
// baseline (403.978 us; speedup 1.0000x reference)
//
#include <hip/hip_runtime.h>

// Depthwise 3D Gaussian conv, 5x5x5, SAME, fp32. x:(2,16,64,128,128) NCDHW.
// Separable: derive 1D marginals of the 3D weight on device (exact, since
// w3 = gz x gy x gx normalized), then fused y/x/z 5-tap passes.
//
// R2 design: NO LDS, NO barriers (R1 was structure-bound at 2.73 TB/s,
// VALUBusy 16%, occupancy 41%: stage->vmcnt->barrier serialization).
//  - y-pass: each thread loads its 5 tap rows directly (L1/L2-resident,
//    6KB/block working set; HBM fetch stays compulsory via L3).
//  - x-pass: 4 lane shuffles (left/right float4 neighbors), no storage.
//  - z-pass: 5-slot named-register ring, 5-step unrolled groups => all
//    static indexing, zero rotation movs (rule #20 safe).
//  - SAME padding: row validity folded into y-weights (clamped addr,
//    zero weight). z bounds: uniform branch. x edges: lane-mask zeros.
// 2048 blocks = 8 blocks/CU, launch_bounds(256,8) => 32 waves/CU.

#define DD 64
#define HH 128
#define WW 128
#define TH 8          // H rows per block
#define NC 16
#define ZCHUNK 16     // z outputs per block
#define SLICE (HH * WW)

typedef float f32x4 __attribute__((ext_vector_type(4)));

__global__ __launch_bounds__(256, 8)
void gauss3d_sep_kernel(const float* __restrict__ x,
                        const float* __restrict__ wt,
                        float* __restrict__ out)
{
    __shared__ float wlds[16];   // wz[0:5], wy[5:10], wx[10:15]

    const int tid  = threadIdx.x;
    const int by   = blockIdx.x * TH;        // 0..120
    const int slab = blockIdx.y;             // 0..31 (n*16+c)
    const int z0   = blockIdx.z * ZCHUNK;    // 0,16,32,48
    const int ch   = slab & (NC - 1);

    const float* xs = x   + (size_t)slab * DD * SLICE;
    float*       os = out + (size_t)slab * DD * SLICE;

    // 1D factors as marginals of the normalized 3D weight (exact).
    if (tid < 15) {
        const int a = tid / 5, q = tid % 5;  // a: 0=z, 1=y, 2=x
        const float* wp = wt + ch * 125;
        float s = 0.f;
        for (int u = 0; u < 5; ++u)
            for (int v = 0; v < 5; ++v) {
                const int i0 = (a == 0) ? q : u;
                const int j0 = (a == 1) ? q : ((a == 0) ? u : v);
                const int k0 = (a == 2) ? q : v;
                s += wp[i0 * 25 + j0 * 5 + k0];
            }
        wlds[a * 5 + q] = s;
    }
    __syncthreads();   // the only barrier in the kernel

    const int ty     = tid >> 5;        // 0..7
    const int lane31 = tid & 31;        // f4-chunk within row
    const int x0     = lane31 << 2;     // 0..124
    const int gy     = by + ty;         // output row, always in [0,128)

    float wzc[5], wxc[5], wyv[5];
    int   roff[5];                      // per-tap row offset within a slice
#pragma unroll
    for (int i = 0; i < 5; ++i) {
        wzc[i] = wlds[i];
        wxc[i] = wlds[10 + i];
        const int  r = gy - 2 + i;
        const bool v = (r >= 0) && (r < HH);
        wyv[i]  = v ? wlds[5 + i] : 0.f;       // fold SAME-pad into weight
        roff[i] = (v ? r : gy) * WW + x0;      // clamped: always in-bounds
    }

    // 5-slot register ring of 2D-convolved slices S[z] (4 cols each).
    float4 r0, r1, r2, r3, r4;
    r0 = r1 = r2 = r3 = r4 = make_float4(0.f, 0.f, 0.f, 0.f);

    const int zbase = z0 - 2;

    // One pipeline step: compute S[zbase+I] into o4; emit out[zs-2] from
    // (o0..o4) = S[zs-4..zs]. Ring slot for step i is r[i%5] => all static.
#define GSTEP(o0, o1, o2, o3, o4, I)                                         \
    {                                                                        \
        const int zs = zbase + (I);                                          \
        float4 sv = make_float4(0.f, 0.f, 0.f, 0.f);                         \
        if ((unsigned)zs < (unsigned)DD) {    /* uniform branch */           \
            const float* sl = xs + (size_t)zs * SLICE;                       \
            float4 yv = make_float4(0.f, 0.f, 0.f, 0.f);                     \
            _Pragma("unroll")                                                \
            for (int dy = 0; dy < 5; ++dy) {                                 \
                const float4 rv = *(const float4*)(sl + roff[dy]);           \
                const float  w  = wyv[dy];                                   \
                yv.x += w * rv.x; yv.y += w * rv.y;                          \
                yv.z += w * rv.z; yv.w += w * rv.w;                          \
            }                                                                \
            float Lz = __shfl(yv.z, tid - 1, 64);                            \
            float Lw = __shfl(yv.w, tid - 1, 64);                            \
            float Rx = __shfl(yv.x, tid + 1, 64);                            \
            float Ry = __shfl(yv.y, tid + 1, 64);                            \
            if (lane31 == 0)  { Lz = 0.f; Lw = 0.f; }                        \
            if (lane31 == 31) { Rx = 0.f; Ry = 0.f; }                        \
            sv.x = wxc[0]*Lz   + wxc[1]*Lw   + wxc[2]*yv.x + wxc[3]*yv.y + wxc[4]*yv.z; \
            sv.y = wxc[0]*Lw   + wxc[1]*yv.x + wxc[2]*yv.y + wxc[3]*yv.z + wxc[4]*yv.w; \
            sv.z = wxc[0]*yv.x + wxc[1]*yv.y + wxc[2]*yv.z + wxc[3]*yv.w + wxc[4]*Rx;   \
            sv.w = wxc[0]*yv.y + wxc[1]*yv.z + wxc[2]*yv.w + wxc[3]*Rx   + wxc[4]*Ry;   \
        }                                                                    \
        o4 = sv;                                                             \
        const int zo = zs - 2;                                               \
        if (zo >= z0) {                       /* uniform; true for I>=4 */   \
            f32x4 ov;                                                        \
            ov.x = wzc[0]*o0.x + wzc[1]*o1.x + wzc[2]*o2.x + wzc[3]*o3.x + wzc[4]*o4.x; \
            ov.y = wzc[0]*o0.y + wzc[1]*o1.y + wzc[2]*o2.y + wzc[3]*o3.y + wzc[4]*o4.y; \
            ov.z = wzc[0]*o0.z + wzc[1]*o1.z + wzc[2]*o2.z + wzc[3]*o3.z + wzc[4]*o4.z; \
            ov.w = wzc[0]*o0.w + wzc[1]*o1.w + wzc[2]*o2.w + wzc[3]*o3.w + wzc[4]*o4.w; \
            f32x4* dst = (f32x4*)(os + (size_t)zo * SLICE + gy * WW + x0);   \
            __builtin_nontemporal_store(ov, dst);  /* output never re-read */ \
        }                                                                    \
    }

    // Prologue group: i = 0..4 (stores fire only at i==4 via zo>=z0).
    GSTEP(r1, r2, r3, r4, r0, 0)
    GSTEP(r2, r3, r4, r0, r1, 1)
    GSTEP(r3, r4, r0, r1, r2, 2)
    GSTEP(r4, r0, r1, r2, r3, 3)
    GSTEP(r0, r1, r2, r3, r4, 4)
    // Steady state: i = 5..19, same 5-step slot rotation.
    for (int g = 5; g < 4 + ZCHUNK; g += 5) {
        GSTEP(r1, r2, r3, r4, r0, g + 0)
        GSTEP(r2, r3, r4, r0, r1, g + 1)
        GSTEP(r3, r4, r0, r1, r2, g + 2)
        GSTEP(r4, r0, r1, r2, r3, g + 3)
        GSTEP(r0, r1, r2, r3, r4, g + 4)
    }
#undef GSTEP
}

extern "C" void kernel_launch(void* const* d_in, const int* in_sizes, int n_in,
                              void* d_out, int out_size, void* d_ws, size_t ws_size,
                              hipStream_t stream)
{
    const float* x = (const float*)d_in[0];   // 2*16*64*128*128 fp32
    const float* w = (const float*)d_in[1];   // 16*1*5*5*5 fp32
    float*       o = (float*)d_out;

    dim3 grid(HH / TH, 2 * NC, DD / ZCHUNK);  // (16, 32, 4) = 2048 blocks
    gauss3d_sep_kernel<<<grid, 256, 0, stream>>>(x, w, o);
}

// Round 5
// 267.992 us; speedup vs baseline: 1.5074x; 1.5074x over previous
//
#include <hip/hip_runtime.h>

// Depthwise 3D Gaussian conv 5x5x5 SAME fp32, x:(2,16,64,128,128) NCDHW.
// Separable (1D marginals derived on device). R4 structure:
//   R1 evidence: LDS-staged single-touch reads => HBM traffic EXACTLY
//     compulsory (135+131 MB) but rate-limited (2.73 TB/s, 2 barriers/slice,
//     loads issued at the barrier, 16 waves/CU).
//   R2 evidence: no-barrier direct reads => waves drift, 5x y-tap re-reads
//     miss cache (FETCH 584 MB), NT stores amplify writes (205 MB). 256 us.
//   R4: keep staging (single-touch), fix the rate:
//     - global_load_lds width=16, linear [12][128] LDS dest (no pad),
//       per-lane clamped global source rows (SAME-pad via zeroed y-weights)
//     - double-buffered: stage slice z+1 at TOP of step, ONE __syncthreads
//       at bottom => HBM latency hides under y/x/z compute (T14 depth-1)
//     - no ybuf: x-halo via lane shuffles (R2-verified); 1 barrier/step
//     - z-pass: static 5-slot register ring, 5-step unrolled groups
//     - plain float4 stores (NT amplified writes in R2)
//     - 12.4 KB LDS, launch_bounds(256,8) => 8 blocks/CU, 32 waves/CU

#define DD 64
#define HH 128
#define WW 128
#define TH 8          // output rows per block
#define NC 16
#define ZCHUNK 16     // z outputs per block (20 steps = 4 groups of 5)
#define SLICE (HH * WW)
#define RAWROWS 12    // TH + 4 halo rows

typedef float f32x4 __attribute__((ext_vector_type(4)));
typedef const __attribute__((address_space(1))) unsigned int g_u32;
typedef __attribute__((address_space(3))) unsigned int l_u32;

__global__ __launch_bounds__(256, 8)
void gauss3d_kernel(const float* __restrict__ x,
                    const float* __restrict__ wt,
                    float* __restrict__ out)
{
    __shared__ float raw[2][RAWROWS][WW];   // 2 x 6 KB, double-buffered slice
    __shared__ float wlds[16];              // wz[0:5], wy[5:10], wx[10:15]

    const int tid  = threadIdx.x;
    const int by   = blockIdx.x * TH;        // 0..120
    const int slab = blockIdx.y;             // 0..31
    const int z0   = blockIdx.z * ZCHUNK;    // 0,16,32,48
    const int ch   = slab & (NC - 1);

    const float* xs = x   + (size_t)slab * DD * SLICE;
    float*       os = out + (size_t)slab * DD * SLICE;

    // 1D factors as marginals of the normalized 3D weight (exact).
    if (tid < 15) {
        const int a = tid / 5, q = tid % 5;  // a: 0=z, 1=y, 2=x
        const float* wp = wt + ch * 125;
        float s = 0.f;
        for (int u = 0; u < 5; ++u)
            for (int v = 0; v < 5; ++v) {
                const int i0 = (a == 0) ? q : u;
                const int j0 = (a == 1) ? q : ((a == 0) ? u : v);
                const int k0 = (a == 2) ? q : v;
                s += wp[i0 * 25 + j0 * 5 + k0];
            }
        wlds[a * 5 + q] = s;
    }

    // Staging map: chunk c (0..383) -> LDS float offset c*4 (linear, so
    // global_load_lds's "uniform base + lane*16" rule holds per wave),
    // global source row clamp(by-2+(c>>5)) col (c&31)*4 (per-lane addr ok).
    const int jr  = tid >> 5;                 // 0..7
    const int cf  = (tid & 31) << 2;          // 0..124 (float col)
    const int g0  = min(max(by - 2 + jr, 0), HH - 1);
    const int so0 = g0 * WW + cf;             // chunk tid
    const int g1  = min(max(by + 6 + jr, 0), HH - 1);   // rows 8..11 (tid<128)
    const int so1 = g1 * WW + cf;             // chunk tid+256

    auto stage = [&](int zs, int b) {
        const float* sl = xs + (size_t)zs * SLICE;
        float* l0 = &raw[b][0][0];
        __builtin_amdgcn_global_load_lds((g_u32*)(sl + so0),
                                         (l_u32*)(l0 + (tid << 2)), 16, 0, 0);
        if (tid < 128)   // waves 0-1 only (uniform per wave)
            __builtin_amdgcn_global_load_lds((g_u32*)(sl + so1),
                                             (l_u32*)(l0 + ((tid + 256) << 2)),
                                             16, 0, 0);
    };

    const int zbase = z0 - 2;
    // Prologue: stage first slice into buf 0; barrier also publishes wlds.
    if ((unsigned)zbase < (unsigned)DD) stage(zbase, 0);
    __syncthreads();

    const int ty = jr;            // thread's output row within tile
    const int x0 = cf;            // thread's 4-col group
    const int gy = by + ty;
    const int lane31 = tid & 31;

    float wzc[5], wxc[5], wyv[5];
#pragma unroll
    for (int i = 0; i < 5; ++i) {
        wzc[i] = wlds[i];
        wxc[i] = wlds[10 + i];
        const int r = gy - 2 + i;
        wyv[i] = (r >= 0 && r < HH) ? wlds[5 + i] : 0.f;  // SAME-pad
    }

    // 5-slot register ring of 2D-convolved slices (static slot rotation).
    float4 r0, r1, r2, r3, r4;
    r0 = r1 = r2 = r3 = r4 = make_float4(0.f, 0.f, 0.f, 0.f);

#define GSTEP(o0, o1, o2, o3, o4, I)                                         \
    {                                                                        \
        const int zs = zbase + (I);                                          \
        if ((unsigned)(zs + 1) < (unsigned)DD)   /* issue next-slice DMA */  \
            stage(zs + 1, ((I) + 1) & 1);                                    \
        float4 sv = make_float4(0.f, 0.f, 0.f, 0.f);                         \
        if ((unsigned)zs < (unsigned)DD) {       /* uniform branch */        \
            const float (*rb)[WW] = raw[(I) & 1];                            \
            float4 yv = make_float4(0.f, 0.f, 0.f, 0.f);                     \
            _Pragma("unroll")                                                \
            for (int dy = 0; dy < 5; ++dy) {                                 \
                const float4 rv = *(const float4*)&rb[ty + dy][x0];          \
                const float  w  = wyv[dy];                                   \
                yv.x += w * rv.x; yv.y += w * rv.y;                          \
                yv.z += w * rv.z; yv.w += w * rv.w;                          \
            }                                                                \
            float Lz = __shfl(yv.z, tid - 1, 64);                            \
            float Lw = __shfl(yv.w, tid - 1, 64);                            \
            float Rx = __shfl(yv.x, tid + 1, 64);                            \
            float Ry = __shfl(yv.y, tid + 1, 64);                            \
            if (lane31 == 0)  { Lz = 0.f; Lw = 0.f; }                        \
            if (lane31 == 31) { Rx = 0.f; Ry = 0.f; }                        \
            sv.x = wxc[0]*Lz   + wxc[1]*Lw   + wxc[2]*yv.x + wxc[3]*yv.y + wxc[4]*yv.z; \
            sv.y = wxc[0]*Lw   + wxc[1]*yv.x + wxc[2]*yv.y + wxc[3]*yv.z + wxc[4]*yv.w; \
            sv.z = wxc[0]*yv.x + wxc[1]*yv.y + wxc[2]*yv.z + wxc[3]*yv.w + wxc[4]*Rx;   \
            sv.w = wxc[0]*yv.y + wxc[1]*yv.z + wxc[2]*yv.w + wxc[3]*Rx   + wxc[4]*Ry;   \
        }                                                                    \
        o4 = sv;                                                             \
        const int zo = zs - 2;                                               \
        if (zo >= z0) {                          /* true from I==4 on */     \
            float4 ov;                                                       \
            ov.x = wzc[0]*o0.x + wzc[1]*o1.x + wzc[2]*o2.x + wzc[3]*o3.x + wzc[4]*o4.x; \
            ov.y = wzc[0]*o0.y + wzc[1]*o1.y + wzc[2]*o2.y + wzc[3]*o3.y + wzc[4]*o4.y; \
            ov.z = wzc[0]*o0.z + wzc[1]*o1.z + wzc[2]*o2.z + wzc[3]*o3.z + wzc[4]*o4.z; \
            ov.w = wzc[0]*o0.w + wzc[1]*o1.w + wzc[2]*o2.w + wzc[3]*o3.w + wzc[4]*o4.w; \
            *(float4*)(os + (size_t)zo * SLICE + (size_t)gy * WW + x0) = ov; \
        }                                                                    \
        __syncthreads();   /* drains staged DMA + publishes buffer swap */   \
    }

    // 20 steps total: prologue group I=0..4 (stores fire from I==4), then
    // 3 steady groups. Slot for step I is r[I%5] => all static indexing.
    GSTEP(r1, r2, r3, r4, r0, 0)
    GSTEP(r2, r3, r4, r0, r1, 1)
    GSTEP(r3, r4, r0, r1, r2, 2)
    GSTEP(r4, r0, r1, r2, r3, 3)
    GSTEP(r0, r1, r2, r3, r4, 4)
    for (int g = 5; g < 4 + ZCHUNK; g += 5) {
        GSTEP(r1, r2, r3, r4, r0, g + 0)
        GSTEP(r2, r3, r4, r0, r1, g + 1)
        GSTEP(r3, r4, r0, r1, r2, g + 2)
        GSTEP(r4, r0, r1, r2, r3, g + 3)
        GSTEP(r0, r1, r2, r3, r4, g + 4)
    }
#undef GSTEP
}

extern "C" void kernel_launch(void* const* d_in, const int* in_sizes, int n_in,
                              void* d_out, int out_size, void* d_ws, size_t ws_size,
                              hipStream_t stream)
{
    const float* x = (const float*)d_in[0];   // 2*16*64*128*128 fp32
    const float* w = (const float*)d_in[1];   // 16*1*5*5*5 fp32
    float*       o = (float*)d_out;

    dim3 grid(HH / TH, 2 * NC, DD / ZCHUNK);  // (16, 32, 4) = 2048 blocks
    gauss3d_kernel<<<grid, 256, 0, stream>>>(x, w, o);
}

// Round 7
// 249.264 us; speedup vs baseline: 1.6207x; 1.0751x over previous
//
#include <hip/hip_runtime.h>

// Depthwise 3D Gaussian conv 5x5x5 SAME fp32, x:(2,16,64,128,128) NCDHW.
// Separable (1D marginals derived on device).
//
// Evidence ledger:
//  R1: LDS-staged, 2 barriers/slice: traffic exactly compulsory, 2.73 TB/s.
//  R2: no barriers, direct loads: waves drift, FETCH 4.3x, 256 us.
//  R4: global_load_lds + 1 __syncthreads/step: FETCH 1.25x (z-halo only),
//      but 110 us @ 3.1 TB/s, VALUBusy 17.6%, occ 80% -> every step all
//      waves drain vmcnt(0) at the barrier: depth-1 pipeline with drain-0.
//  R5: WAVE-AUTONOMOUS pipeline. Each wave stages its OWN 6-row window
//      (2 out rows + 4 halo) via global_load_lds into wave-private LDS,
//      double-buffered; waits are COUNTED vmcnt (3 prologue / 4 steady,
//      never 0) so next-slice DMA stays in flight across compute; a RAW
//      s_barrier per step (no waitcnt drain) only limits wave drift so
//      halo overlap stays L2-warm. Store issued after compute; vmcnt
//      retires in issue order so vmcnt(4) == "z's 3 DMAs retired".
//      24KB LDS/block -> 6 blocks/CU = 24 waves/CU.

#define DD 64
#define HH 128
#define WW 128
#define NC 16
#define ZCHUNK 16
#define SLICE (HH * WW)

typedef const __attribute__((address_space(1))) unsigned int g_u32;
typedef __attribute__((address_space(3))) unsigned int l_u32;

__global__ __launch_bounds__(256, 6)
void gauss3d_kernel(const float* __restrict__ x,
                    const float* __restrict__ wt,
                    float* __restrict__ out)
{
    // Wave-private staging: [wave][buf][6 rows][128 cols]
    __shared__ float raw[4][2][6][WW];     // 24 KB
    __shared__ float wlds[16];             // wz[0:5], wy[5:10], wx[10:15]

    const int tid  = threadIdx.x;
    const int w    = tid >> 6;               // wave 0..3
    const int lane = tid & 63;
    const int by   = blockIdx.x * 8;         // 8 output rows per block
    const int slab = blockIdx.y;             // 0..31
    const int z0   = blockIdx.z * ZCHUNK;    // 0,16,32,48
    const int ch   = slab & (NC - 1);

    const float* xs = x   + (size_t)slab * DD * SLICE;
    float*       os = out + (size_t)slab * DD * SLICE;

    // 1D factors as marginals of the normalized 3D weight (exact).
    if (tid < 15) {
        const int a = tid / 5, q = tid % 5;  // a: 0=z, 1=y, 2=x
        const float* wp = wt + ch * 125;
        float s = 0.f;
        for (int u = 0; u < 5; ++u)
            for (int v = 0; v < 5; ++v) {
                const int i0 = (a == 0) ? q : u;
                const int j0 = (a == 1) ? q : ((a == 0) ? u : v);
                const int k0 = (a == 2) ? q : v;
                s += wp[i0 * 25 + j0 * 5 + k0];
            }
        wlds[a * 5 + q] = s;
    }
    __syncthreads();   // publishes wlds; BEFORE any DMA is issued (no drain cost)

    const int sub    = lane >> 5;            // row within pair (0/1)
    const int lane31 = lane & 31;
    const int col    = lane31 << 2;          // float col 0..124
    const int wy0    = by + w * 2;           // wave's first output row
    const int gy     = wy0 + sub;            // this thread's output row

    // Per-wave staging source offsets: window rows wy0-2 .. wy0+3 (clamped;
    // SAME-pad handled by zeroed y-weights). DMA k covers window rows 2k,2k+1.
    int so[3];
#pragma unroll
    for (int k = 0; k < 3; ++k) {
        const int gr = min(max(wy0 - 2 + 2 * k + sub, 0), HH - 1);
        so[k] = gr * WW + col;
    }

    float wzc[5], wxc[5], wyv[5];
#pragma unroll
    for (int i = 0; i < 5; ++i) {
        wzc[i] = wlds[i];
        wxc[i] = wlds[10 + i];
        const int r = gy - 2 + i;
        wyv[i] = (r >= 0 && r < HH) ? wlds[5 + i] : 0.f;
    }

    const int zbase = z0 - 2;

    // Always-issue staging (z clamped) => uniform vmcnt accounting: 3/step.
#define STAGE(ZS, B)                                                         \
    {                                                                        \
        const int zc = min(max((ZS), 0), DD - 1);                            \
        const float* sl = xs + (size_t)zc * SLICE;                           \
        _Pragma("unroll")                                                    \
        for (int k = 0; k < 3; ++k)                                          \
            __builtin_amdgcn_global_load_lds((g_u32*)(sl + so[k]),           \
                (l_u32*)(&raw[w][(B)][2 * k][0]), 16, 0, 0);                 \
    }

    // 5-slot register ring of 2D-convolved slices (static slot rotation).
    float4 r0, r1, r2, r3, r4;
    r0 = r1 = r2 = r3 = r4 = make_float4(0.f, 0.f, 0.f, 0.f);

    STAGE(zbase, 0)

    // Step I: stage z+1 into buf (I+1)&1; counted wait for z's 3 DMAs
    // (WAIT=3 before any store is outstanding, 4 after); compute slice z
    // from buf I&1; ring-rotate; store z-2; raw barrier (anti-drift, NO
    // waitcnt drain).
#define GSTEP(o0, o1, o2, o3, o4, I, WAIT)                                   \
    {                                                                        \
        const int zs = zbase + (I);                                          \
        STAGE(zs + 1, ((I) + 1) & 1)                                         \
        asm volatile("s_waitcnt vmcnt(" #WAIT ")" ::: "memory");             \
        __builtin_amdgcn_sched_barrier(0);                                   \
        float4 sv = make_float4(0.f, 0.f, 0.f, 0.f);                         \
        if ((unsigned)zs < (unsigned)DD) {       /* uniform branch */        \
            const float (*rb)[WW] = raw[w][(I) & 1];                         \
            float4 yv = make_float4(0.f, 0.f, 0.f, 0.f);                     \
            _Pragma("unroll")                                                \
            for (int dy = 0; dy < 5; ++dy) {                                 \
                const float4 rv = *(const float4*)&rb[sub + dy][col];        \
                const float  wq = wyv[dy];                                   \
                yv.x += wq * rv.x; yv.y += wq * rv.y;                        \
                yv.z += wq * rv.z; yv.w += wq * rv.w;                        \
            }                                                                \
            float Lz = __shfl(yv.z, tid - 1, 64);                            \
            float Lw = __shfl(yv.w, tid - 1, 64);                            \
            float Rx = __shfl(yv.x, tid + 1, 64);                            \
            float Ry = __shfl(yv.y, tid + 1, 64);                            \
            if (lane31 == 0)  { Lz = 0.f; Lw = 0.f; }                        \
            if (lane31 == 31) { Rx = 0.f; Ry = 0.f; }                        \
            sv.x = wxc[0]*Lz   + wxc[1]*Lw   + wxc[2]*yv.x + wxc[3]*yv.y + wxc[4]*yv.z; \
            sv.y = wxc[0]*Lw   + wxc[1]*yv.x + wxc[2]*yv.y + wxc[3]*yv.z + wxc[4]*yv.w; \
            sv.z = wxc[0]*yv.x + wxc[1]*yv.y + wxc[2]*yv.z + wxc[3]*yv.w + wxc[4]*Rx;   \
            sv.w = wxc[0]*yv.y + wxc[1]*yv.z + wxc[2]*yv.w + wxc[3]*Rx   + wxc[4]*Ry;   \
        }                                                                    \
        o4 = sv;                                                             \
        const int zo = zs - 2;                                               \
        if (zo >= z0) {                          /* uniform; I>=4 */         \
            float4 ov;                                                       \
            ov.x = wzc[0]*o0.x + wzc[1]*o1.x + wzc[2]*o2.x + wzc[3]*o3.x + wzc[4]*o4.x; \
            ov.y = wzc[0]*o0.y + wzc[1]*o1.y + wzc[2]*o2.y + wzc[3]*o3.y + wzc[4]*o4.y; \
            ov.z = wzc[0]*o0.z + wzc[1]*o1.z + wzc[2]*o2.z + wzc[3]*o3.z + wzc[4]*o4.z; \
            ov.w = wzc[0]*o0.w + wzc[1]*o1.w + wzc[2]*o2.w + wzc[3]*o3.w + wzc[4]*o4.w; \
            *(float4*)(os + (size_t)zo * SLICE + (size_t)gy * WW + col) = ov;\
        }                                                                    \
        __builtin_amdgcn_s_barrier();   /* raw: aligns waves, drains nothing */ \
    }

    // 20 steps; outputs fire from I==4. Ring slot for step I is r[I%5].
    GSTEP(r1, r2, r3, r4, r0, 0, 3)
    GSTEP(r2, r3, r4, r0, r1, 1, 3)
    GSTEP(r3, r4, r0, r1, r2, 2, 3)
    GSTEP(r4, r0, r1, r2, r3, 3, 3)
    GSTEP(r0, r1, r2, r3, r4, 4, 3)   // first store at end of this step
    GSTEP(r1, r2, r3, r4, r0, 5, 4)
    GSTEP(r2, r3, r4, r0, r1, 6, 4)
    GSTEP(r3, r4, r0, r1, r2, 7, 4)
    GSTEP(r4, r0, r1, r2, r3, 8, 4)
    GSTEP(r0, r1, r2, r3, r4, 9, 4)
    GSTEP(r1, r2, r3, r4, r0, 10, 4)
    GSTEP(r2, r3, r4, r0, r1, 11, 4)
    GSTEP(r3, r4, r0, r1, r2, 12, 4)
    GSTEP(r4, r0, r1, r2, r3, 13, 4)
    GSTEP(r0, r1, r2, r3, r4, 14, 4)
    GSTEP(r1, r2, r3, r4, r0, 15, 4)
    GSTEP(r2, r3, r4, r0, r1, 16, 4)
    GSTEP(r3, r4, r0, r1, r2, 17, 4)
    GSTEP(r4, r0, r1, r2, r3, 18, 4)
    GSTEP(r0, r1, r2, r3, r4, 19, 4)
#undef GSTEP
#undef STAGE
}

extern "C" void kernel_launch(void* const* d_in, const int* in_sizes, int n_in,
                              void* d_out, int out_size, void* d_ws, size_t ws_size,
                              hipStream_t stream)
{
    const float* x = (const float*)d_in[0];   // 2*16*64*128*128 fp32
    const float* w = (const float*)d_in[1];   // 16*1*5*5*5 fp32
    float*       o = (float*)d_out;

    dim3 grid(HH / 8, 2 * NC, DD / ZCHUNK);   // (16, 32, 4) = 2048 blocks
    gauss3d_kernel<<<grid, 256, 0, stream>>>(x, w, o);
}

// Round 8
// 247.336 us; speedup vs baseline: 1.6333x; 1.0078x over previous
//
#include <hip/hip_runtime.h>

// Depthwise 3D Gaussian conv 5x5x5 SAME fp32, x:(2,16,64,128,128) NCDHW.
// Separable (1D marginals derived on device).
//
// Evidence ledger:
//  R1: block-LDS, 2 full barriers/slice: traffic compulsory, 2.73 TB/s.
//  R2: no barriers: wave drift, FETCH 4.3x, 256 us.
//  R4: gload_lds + __syncthreads/step: FETCH 1.25x, 110 us (drain-0 stall).
//  R5: wave-private staging, counted vmcnt, raw s_barrier: FETCH 112 MB
//      (sub-compulsory, L3 absorbs halo), 92.5 us @ 2.68 TB/s BUT
//      occupancy 48%: 6 resident vs 8 blocks/CU of work -> TWO BATCHES
//      (6 then tail of 2). Tail model reproduces occ 48 / 2.6 TB/s / 2x dur.
//  R7: single batch: 128-thread blocks (2 waves x 4 rows, 8-row window,
//      4 DMAs/step), 16.4 KB LDS -> 8 blocks/CU resident == 8/CU of work.
//      Fatter waves: 7 shared ds_read_b128 feed 2 output rows. Counted
//      vmcnt 4/6 (never 0). XCD-bijective swizzle for y-halo L2 locality.

#define DD 64
#define HH 128
#define WW 128
#define NC 16
#define ZCHUNK 16
#define SLICE (HH * WW)

typedef const __attribute__((address_space(1))) unsigned int g_u32;
typedef __attribute__((address_space(3))) unsigned int l_u32;

__global__ __launch_bounds__(128, 4)
void gauss3d_kernel(const float* __restrict__ x,
                    const float* __restrict__ wt,
                    float* __restrict__ out)
{
    // Wave-private staging: [wave][buf][8 rows][128 cols] = 16 KB
    __shared__ float raw[2][2][8][WW];
    __shared__ float wlds[16];             // wz[0:5], wy[5:10], wx[10:15]

    const int tid  = threadIdx.x;
    const int wv   = tid >> 6;               // wave 0..1
    const int lane = tid & 63;

    // XCD-bijective swizzle (nwg=2048, 2048%8==0): hw-flat id f runs
    // round-robin over 8 XCDs; remap so each XCD owns 256 logically-
    // contiguous blocks (all 16 y-tiles of 16 slabs at one z-chunk) =>
    // y-halo-sharing neighbors stay on one XCD's L2.
    const int f  = blockIdx.x + (blockIdx.y << 4) + (blockIdx.z << 9);
    const int g  = ((f & 7) << 8) + (f >> 3);
    const int by   = (g & 15) * 8;           // y-tile base row
    const int slab = (g >> 4) & 31;          // n*16+c
    const int z0   = (g >> 9) * ZCHUNK;      // 0,16,32,48
    const int ch   = slab & (NC - 1);

    const float* xs = x   + (size_t)slab * DD * SLICE;
    float*       os = out + (size_t)slab * DD * SLICE;

    // 1D factors as marginals of the normalized 3D weight (exact).
    if (tid < 15) {
        const int a = tid / 5, q = tid % 5;  // a: 0=z, 1=y, 2=x
        const float* wp = wt + ch * 125;
        float s = 0.f;
        for (int u = 0; u < 5; ++u)
            for (int v = 0; v < 5; ++v) {
                const int i0 = (a == 0) ? q : u;
                const int j0 = (a == 1) ? q : ((a == 0) ? u : v);
                const int k0 = (a == 2) ? q : v;
                s += wp[i0 * 25 + j0 * 5 + k0];
            }
        wlds[a * 5 + q] = s;
    }
    __syncthreads();   // publishes wlds (before any VMEM: no drain cost)

    const int sub    = lane >> 5;            // 0/1: row within pair
    const int lane31 = lane & 31;
    const int col    = lane31 << 2;          // float col 0..124
    const int wy0    = by + wv * 4;          // wave's first output row
    const int gyA    = wy0 + sub;            // thread's output rows:
    const int gyB    = wy0 + sub + 2;        //   gyA and gyA+2

    // Staging: window rows wy0-2..wy0+5 (clamped). DMA k covers window
    // rows 2k,2k+1: lane sub picks the row, lane31 the 16B column.
    int so[4];
#pragma unroll
    for (int k = 0; k < 4; ++k) {
        const int gr = min(max(wy0 - 2 + 2 * k + sub, 0), HH - 1);
        so[k] = gr * WW + col;
    }

    float wzc[5], wxc[5], wyvA[5], wyvB[5];
#pragma unroll
    for (int i = 0; i < 5; ++i) {
        wzc[i] = wlds[i];
        wxc[i] = wlds[10 + i];
        const int ra = gyA - 2 + i;
        const int rb_ = gyB - 2 + i;
        wyvA[i] = (ra  >= 0 && ra  < HH) ? wlds[5 + i] : 0.f;  // SAME-pad
        wyvB[i] = (rb_ >= 0 && rb_ < HH) ? wlds[5 + i] : 0.f;
    }

    const int zbase = z0 - 2;

#define STAGE(ZS, B)                                                         \
    {                                                                        \
        const int zc = min(max((ZS), 0), DD - 1);                            \
        const float* sl = xs + (size_t)zc * SLICE;                           \
        _Pragma("unroll")                                                    \
        for (int k = 0; k < 4; ++k)                                          \
            __builtin_amdgcn_global_load_lds((g_u32*)(sl + so[k]),           \
                (l_u32*)(&raw[wv][(B)][2 * k][0]), 16, 0, 0);                 \
    }

    const float4 zero4 = make_float4(0.f, 0.f, 0.f, 0.f);

    // x-pass: 5-tap in W via 4 lane shuffles (float4 neighbors).
    auto xp = [&](const float4& yv) -> float4 {
        float Lz = __shfl(yv.z, lane - 1, 64);
        float Lw = __shfl(yv.w, lane - 1, 64);
        float Rx = __shfl(yv.x, lane + 1, 64);
        float Ry = __shfl(yv.y, lane + 1, 64);
        if (lane31 == 0)  { Lz = 0.f; Lw = 0.f; }
        if (lane31 == 31) { Rx = 0.f; Ry = 0.f; }
        float4 s;
        s.x = wxc[0]*Lz   + wxc[1]*Lw   + wxc[2]*yv.x + wxc[3]*yv.y + wxc[4]*yv.z;
        s.y = wxc[0]*Lw   + wxc[1]*yv.x + wxc[2]*yv.y + wxc[3]*yv.z + wxc[4]*yv.w;
        s.z = wxc[0]*yv.x + wxc[1]*yv.y + wxc[2]*yv.z + wxc[3]*yv.w + wxc[4]*Rx;
        s.w = wxc[0]*yv.y + wxc[1]*yv.z + wxc[2]*yv.w + wxc[3]*Rx   + wxc[4]*Ry;
        return s;
    };

    // Two 5-slot register rings (rows A,B), static slot rotation.
    float4 a0, a1, a2, a3, a4, b0, b1, b2, b3, b4;
    a0 = a1 = a2 = a3 = a4 = zero4;
    b0 = b1 = b2 = b3 = b4 = zero4;

    STAGE(zbase, 0)

    // Step I: stage z+1 -> buf (I+1)&1; counted wait for z's 4 DMAs
    // (issued step I-1: coverage = one full step); 7 shared ds_read_b128
    // feed both row-convs; 2 stores; raw s_barrier (anti-drift, no drain).
#define GSTEP(A0, A1, A2, A3, A4, B0, B1, B2, B3, B4, I, W)                  \
    {                                                                        \
        const int zs = zbase + (I);                                          \
        STAGE(zs + 1, ((I) + 1) & 1)                                         \
        asm volatile("s_waitcnt vmcnt(" #W ")" ::: "memory");                \
        __builtin_amdgcn_sched_barrier(0);                                   \
        float4 svA = zero4, svB = zero4;                                     \
        if ((unsigned)zs < (unsigned)DD) {       /* uniform branch */        \
            const float (*rb)[WW] = raw[wv][(I) & 1];                        \
            float4 h[7];                                                     \
            _Pragma("unroll")                                                \
            for (int j = 0; j < 7; ++j)                                      \
                h[j] = *(const float4*)&rb[sub + j][col];                    \
            float4 yA = zero4, yB = zero4;                                   \
            _Pragma("unroll")                                                \
            for (int i = 0; i < 5; ++i) {                                    \
                const float wa = wyvA[i], wb = wyvB[i];                      \
                yA.x += wa * h[i].x;     yA.y += wa * h[i].y;                \
                yA.z += wa * h[i].z;     yA.w += wa * h[i].w;                \
                yB.x += wb * h[i + 2].x; yB.y += wb * h[i + 2].y;            \
                yB.z += wb * h[i + 2].z; yB.w += wb * h[i + 2].w;            \
            }                                                                \
            svA = xp(yA);                                                    \
            svB = xp(yB);                                                    \
        }                                                                    \
        A4 = svA; B4 = svB;                                                  \
        const int zo = zs - 2;                                               \
        if (zo >= z0) {                          /* uniform; I>=4 */         \
            float4 oA, oB;                                                   \
            oA.x = wzc[0]*A0.x + wzc[1]*A1.x + wzc[2]*A2.x + wzc[3]*A3.x + wzc[4]*A4.x; \
            oA.y = wzc[0]*A0.y + wzc[1]*A1.y + wzc[2]*A2.y + wzc[3]*A3.y + wzc[4]*A4.y; \
            oA.z = wzc[0]*A0.z + wzc[1]*A1.z + wzc[2]*A2.z + wzc[3]*A3.z + wzc[4]*A4.z; \
            oA.w = wzc[0]*A0.w + wzc[1]*A1.w + wzc[2]*A2.w + wzc[3]*A3.w + wzc[4]*A4.w; \
            oB.x = wzc[0]*B0.x + wzc[1]*B1.x + wzc[2]*B2.x + wzc[3]*B3.x + wzc[4]*B4.x; \
            oB.y = wzc[0]*B0.y + wzc[1]*B1.y + wzc[2]*B2.y + wzc[3]*B3.y + wzc[4]*B4.y; \
            oB.z = wzc[0]*B0.z + wzc[1]*B1.z + wzc[2]*B2.z + wzc[3]*B3.z + wzc[4]*B4.z; \
            oB.w = wzc[0]*B0.w + wzc[1]*B1.w + wzc[2]*B2.w + wzc[3]*B3.w + wzc[4]*B4.w; \
            *(float4*)(os + (size_t)zo * SLICE + (size_t)gyA * WW + col) = oA; \
            *(float4*)(os + (size_t)zo * SLICE + (size_t)gyB * WW + col) = oB; \
        }                                                                    \
        __builtin_amdgcn_s_barrier();   /* raw: aligns waves, drains nothing */ \
    }

    // vmcnt ledger (per wave; issue order: [z DMAs x4][2 stores][z+1 DMAs x4]):
    //  steps 0..4: no stores outstanding at wait -> W=4
    //  steps 5..19: 2 stores from step I-1 -> W=6
    GSTEP(a1, a2, a3, a4, a0, b1, b2, b3, b4, b0, 0, 4)
    GSTEP(a2, a3, a4, a0, a1, b2, b3, b4, b0, b1, 1, 4)
    GSTEP(a3, a4, a0, a1, a2, b3, b4, b0, b1, b2, 2, 4)
    GSTEP(a4, a0, a1, a2, a3, b4, b0, b1, b2, b3, 3, 4)
    GSTEP(a0, a1, a2, a3, a4, b0, b1, b2, b3, b4, 4, 4)   // first stores
    GSTEP(a1, a2, a3, a4, a0, b1, b2, b3, b4, b0, 5, 6)
    GSTEP(a2, a3, a4, a0, a1, b2, b3, b4, b0, b1, 6, 6)
    GSTEP(a3, a4, a0, a1, a2, b3, b4, b0, b1, b2, 7, 6)
    GSTEP(a4, a0, a1, a2, a3, b4, b0, b1, b2, b3, 8, 6)
    GSTEP(a0, a1, a2, a3, a4, b0, b1, b2, b3, b4, 9, 6)
    GSTEP(a1, a2, a3, a4, a0, b1, b2, b3, b4, b0, 10, 6)
    GSTEP(a2, a3, a4, a0, a1, b2, b3, b4, b0, b1, 11, 6)
    GSTEP(a3, a4, a0, a1, a2, b3, b4, b0, b1, b2, 12, 6)
    GSTEP(a4, a0, a1, a2, a3, b4, b0, b1, b2, b3, 13, 6)
    GSTEP(a0, a1, a2, a3, a4, b0, b1, b2, b3, b4, 14, 6)
    GSTEP(a1, a2, a3, a4, a0, b1, b2, b3, b4, b0, 15, 6)
    GSTEP(a2, a3, a4, a0, a1, b2, b3, b4, b0, b1, 16, 6)
    GSTEP(a3, a4, a0, a1, a2, b3, b4, b0, b1, b2, 17, 6)
    GSTEP(a4, a0, a1, a2, a3, b4, b0, b1, b2, b3, 18, 6)
    GSTEP(a0, a1, a2, a3, a4, b0, b1, b2, b3, b4, 19, 6)
#undef GSTEP
#undef STAGE
}

extern "C" void kernel_launch(void* const* d_in, const int* in_sizes, int n_in,
                              void* d_out, int out_size, void* d_ws, size_t ws_size,
                              hipStream_t stream)
{
    const float* x = (const float*)d_in[0];   // 2*16*64*128*128 fp32
    const float* w = (const float*)d_in[1];   // 16*1*5*5*5 fp32
    float*       o = (float*)d_out;

    dim3 grid(HH / 8, 2 * NC, DD / ZCHUNK);   // (16, 32, 4) = 2048 blocks
    gauss3d_kernel<<<grid, 128, 0, stream>>>(x, w, o);
}

// Round 9
// 241.136 us; speedup vs baseline: 1.6753x; 1.0257x over previous
//
#include <hip/hip_runtime.h>

// Depthwise 3D Gaussian conv 5x5x5 SAME fp32, x:(2,16,64,128,128) NCDHW.
// Separable (1D marginals derived on device).
//
// Evidence ledger:
//  R1: block-LDS, full barriers: compulsory traffic, 2.73 TB/s, 99.8 us.
//  R2: free-run direct loads: L2-miss traffic 4.3x, rate 3.16 TB/s, 256 us.
//  R4: gload_lds + __syncthreads/step (drain-0): 110 us.
//  R5: wave-private dbuf + counted vmcnt + raw barrier: 92.5 us, 2.68 TB/s,
//      occ 48% (6 resident vs 8 work -> tail).
//  R7: 2-wave blocks, 8/CU: 91 us, 2.4 TB/s, occ 36.5%. Staged designs pin
//      at 2.4-2.7 TB/s: depth-1 convoy exposes latency+queueing every step.
//  R8 (H1 test): DEPTH-2 pipeline: 3 wave-private buffers, stage z+2 while
//      computing z (coverage = 2 full steps > HBM latency); ZCHUNK=32;
//      512 blocks = EXACTLY 2 resident/CU (single batch, no tail);
//      vmcnt 8/10/12 never 0; raw s_barrier per step (anti-drift only).
//      If this stays ~90 us @ 2.5 TB/s -> rate pin (H2) confirmed.

#define DD 64
#define HH 128
#define WW 128
#define NC 16
#define ZCHUNK 32
#define SLICE (HH * WW)

typedef const __attribute__((address_space(1))) unsigned int g_u32;
typedef __attribute__((address_space(3))) unsigned int l_u32;

__global__ __launch_bounds__(256, 2)
void gauss3d_kernel(const float* __restrict__ x,
                    const float* __restrict__ wt,
                    float* __restrict__ out)
{
    // Wave-private staging: [wave][buf=3][8 rows][128 cols] = 48 KB/block
    __shared__ float raw[4][3][8][WW];
    __shared__ float wlds[16];             // wz[0:5], wy[5:10], wx[10:15]

    const int tid  = threadIdx.x;
    const int wv   = tid >> 6;               // wave 0..3
    const int lane = tid & 63;

    // XCD-bijective swizzle (512 blocks, 64/XCD = 2/CU exactly).
    // XCD x owns g in [64x,64x+64): all 8 y-tiles of 8 slabs, one z-chunk
    // => y-halo-sharing neighbors stay in one XCD's L2.
    const int f  = blockIdx.x + (blockIdx.y << 3) + (blockIdx.z << 8);
    const int g  = ((f & 7) << 6) | (f >> 3);
    const int by   = (g & 7) * 16;           // y-tile base row (16 rows/block)
    const int slab = (g >> 3) & 31;          // n*16+c
    const int z0   = (g >> 8) * ZCHUNK;      // 0 or 32
    const int ch   = slab & (NC - 1);

    const float* xs = x   + (size_t)slab * DD * SLICE;
    float*       os = out + (size_t)slab * DD * SLICE;

    // 1D factors as marginals of the normalized 3D weight (exact).
    if (tid < 15) {
        const int a = tid / 5, q = tid % 5;  // a: 0=z, 1=y, 2=x
        const float* wp = wt + ch * 125;
        float s = 0.f;
        for (int u = 0; u < 5; ++u)
            for (int v = 0; v < 5; ++v) {
                const int i0 = (a == 0) ? q : u;
                const int j0 = (a == 1) ? q : ((a == 0) ? u : v);
                const int k0 = (a == 2) ? q : v;
                s += wp[i0 * 25 + j0 * 5 + k0];
            }
        wlds[a * 5 + q] = s;
    }
    __syncthreads();   // publishes wlds (before any VMEM: no drain cost)

    const int sub    = lane >> 5;            // 0/1: row within pair
    const int lane31 = lane & 31;
    const int col    = lane31 << 2;          // float col 0..124
    const int wy0    = by + wv * 4;          // wave's first output row
    const int gyA    = wy0 + sub;            // thread's output rows:
    const int gyB    = wy0 + sub + 2;        //   gyA and gyA+2

    // Staging: window rows wy0-2..wy0+5 (clamped). DMA k covers window
    // rows 2k,2k+1: lane sub picks the row, lane31 the 16B column.
    int so[4];
#pragma unroll
    for (int k = 0; k < 4; ++k) {
        const int gr = min(max(wy0 - 2 + 2 * k + sub, 0), HH - 1);
        so[k] = gr * WW + col;
    }

    float wzc[5], wxc[5], wyvA[5], wyvB[5];
#pragma unroll
    for (int i = 0; i < 5; ++i) {
        wzc[i] = wlds[i];
        wxc[i] = wlds[10 + i];
        const int ra = gyA - 2 + i;
        const int rb_ = gyB - 2 + i;
        wyvA[i] = (ra  >= 0 && ra  < HH) ? wlds[5 + i] : 0.f;  // SAME-pad
        wyvB[i] = (rb_ >= 0 && rb_ < HH) ? wlds[5 + i] : 0.f;
    }

    const int zbase = z0 - 2;

    // Always-issue staging (z clamped) => uniform vmcnt: 4 DMAs/step.
#define STAGE(ZS, B)                                                         \
    {                                                                        \
        const int zc = min(max((ZS), 0), DD - 1);                            \
        const float* sl = xs + (size_t)zc * SLICE;                           \
        _Pragma("unroll")                                                    \
        for (int k = 0; k < 4; ++k)                                          \
            __builtin_amdgcn_global_load_lds((g_u32*)(sl + so[k]),           \
                (l_u32*)(&raw[wv][(B)][2 * k][0]), 16, 0, 0);                 \
    }

    const float4 zero4 = make_float4(0.f, 0.f, 0.f, 0.f);

    // x-pass: 5-tap in W via 4 lane shuffles (float4 neighbors).
    auto xp = [&](const float4& yv) -> float4 {
        float Lz = __shfl(yv.z, lane - 1, 64);
        float Lw = __shfl(yv.w, lane - 1, 64);
        float Rx = __shfl(yv.x, lane + 1, 64);
        float Ry = __shfl(yv.y, lane + 1, 64);
        if (lane31 == 0)  { Lz = 0.f; Lw = 0.f; }
        if (lane31 == 31) { Rx = 0.f; Ry = 0.f; }
        float4 s;
        s.x = wxc[0]*Lz   + wxc[1]*Lw   + wxc[2]*yv.x + wxc[3]*yv.y + wxc[4]*yv.z;
        s.y = wxc[0]*Lw   + wxc[1]*yv.x + wxc[2]*yv.y + wxc[3]*yv.z + wxc[4]*yv.w;
        s.z = wxc[0]*yv.x + wxc[1]*yv.y + wxc[2]*yv.z + wxc[3]*yv.w + wxc[4]*Rx;
        s.w = wxc[0]*yv.y + wxc[1]*yv.z + wxc[2]*yv.w + wxc[3]*Rx   + wxc[4]*Ry;
        return s;
    };

    // Two 5-slot register rings (rows A,B), static slot rotation.
    float4 a0, a1, a2, a3, a4, b0, b1, b2, b3, b4;
    a0 = a1 = a2 = a3 = a4 = zero4;
    b0 = b1 = b2 = b3 = b4 = zero4;

    // Depth-2 prologue: buffers 0,1 <- slices zbase, zbase+1.
    STAGE(zbase, 0)
    STAGE(zbase + 1, 1)

    // Step I: stage slice zbase+I+2 into buf (I+2)%3; counted wait for
    // slice zbase+I's 4 DMAs (issued at step I-2: coverage = TWO steps);
    // compute from buf I%3; 2 stores; raw s_barrier (anti-drift, no drain).
    // vmcnt ledger (issue order ... D_I, [S_{I-2}], D_{I+1}, [S_{I-1}], D_{I+2}, WAIT):
    //   I<=4: W=8 (no stores yet); I=5: W=10; I>=6: W=12.
#define GSTEP(A0, A1, A2, A3, A4, B0, B1, B2, B3, B4, I, W)                  \
    {                                                                        \
        const int zs = zbase + (I);                                          \
        STAGE(zs + 2, ((I) + 2) % 3)                                         \
        asm volatile("s_waitcnt vmcnt(" #W ")" ::: "memory");                \
        __builtin_amdgcn_sched_barrier(0);                                   \
        float4 svA = zero4, svB = zero4;                                     \
        if ((unsigned)zs < (unsigned)DD) {       /* uniform branch */        \
            const float (*rb)[WW] = raw[wv][(I) % 3];                        \
            float4 h[7];                                                     \
            _Pragma("unroll")                                                \
            for (int j = 0; j < 7; ++j)                                      \
                h[j] = *(const float4*)&rb[sub + j][col];                    \
            float4 yA = zero4, yB = zero4;                                   \
            _Pragma("unroll")                                                \
            for (int i = 0; i < 5; ++i) {                                    \
                const float wa = wyvA[i], wb = wyvB[i];                      \
                yA.x += wa * h[i].x;     yA.y += wa * h[i].y;                \
                yA.z += wa * h[i].z;     yA.w += wa * h[i].w;                \
                yB.x += wb * h[i + 2].x; yB.y += wb * h[i + 2].y;            \
                yB.z += wb * h[i + 2].z; yB.w += wb * h[i + 2].w;            \
            }                                                                \
            svA = xp(yA);                                                    \
            svB = xp(yB);                                                    \
        }                                                                    \
        A4 = svA; B4 = svB;                                                  \
        const int zo = zs - 2;                                               \
        if (zo >= z0) {                          /* uniform; I>=4 */         \
            float4 oA, oB;                                                   \
            oA.x = wzc[0]*A0.x + wzc[1]*A1.x + wzc[2]*A2.x + wzc[3]*A3.x + wzc[4]*A4.x; \
            oA.y = wzc[0]*A0.y + wzc[1]*A1.y + wzc[2]*A2.y + wzc[3]*A3.y + wzc[4]*A4.y; \
            oA.z = wzc[0]*A0.z + wzc[1]*A1.z + wzc[2]*A2.z + wzc[3]*A3.z + wzc[4]*A4.z; \
            oA.w = wzc[0]*A0.w + wzc[1]*A1.w + wzc[2]*A2.w + wzc[3]*A3.w + wzc[4]*A4.w; \
            oB.x = wzc[0]*B0.x + wzc[1]*B1.x + wzc[2]*B2.x + wzc[3]*B3.x + wzc[4]*B4.x; \
            oB.y = wzc[0]*B0.y + wzc[1]*B1.y + wzc[2]*B2.y + wzc[3]*B3.y + wzc[4]*B4.y; \
            oB.z = wzc[0]*B0.z + wzc[1]*B1.z + wzc[2]*B2.z + wzc[3]*B3.z + wzc[4]*B4.z; \
            oB.w = wzc[0]*B0.w + wzc[1]*B1.w + wzc[2]*B2.w + wzc[3]*B3.w + wzc[4]*B4.w; \
            *(float4*)(os + (size_t)zo * SLICE + (size_t)gyA * WW + col) = oA; \
            *(float4*)(os + (size_t)zo * SLICE + (size_t)gyB * WW + col) = oB; \
        }                                                                    \
        __builtin_amdgcn_s_barrier();   /* raw: aligns waves, drains nothing */ \
    }

    // 36 steps (z = z0-2 .. z0+33); outputs fire from I==4.
    GSTEP(a1, a2, a3, a4, a0, b1, b2, b3, b4, b0, 0, 8)
    GSTEP(a2, a3, a4, a0, a1, b2, b3, b4, b0, b1, 1, 8)
    GSTEP(a3, a4, a0, a1, a2, b3, b4, b0, b1, b2, 2, 8)
    GSTEP(a4, a0, a1, a2, a3, b4, b0, b1, b2, b3, 3, 8)
    GSTEP(a0, a1, a2, a3, a4, b0, b1, b2, b3, b4, 4, 8)   // first stores
    GSTEP(a1, a2, a3, a4, a0, b1, b2, b3, b4, b0, 5, 10)
    GSTEP(a2, a3, a4, a0, a1, b2, b3, b4, b0, b1, 6, 12)
    GSTEP(a3, a4, a0, a1, a2, b3, b4, b0, b1, b2, 7, 12)
    GSTEP(a4, a0, a1, a2, a3, b4, b0, b1, b2, b3, 8, 12)
    GSTEP(a0, a1, a2, a3, a4, b0, b1, b2, b3, b4, 9, 12)
    GSTEP(a1, a2, a3, a4, a0, b1, b2, b3, b4, b0, 10, 12)
    GSTEP(a2, a3, a4, a0, a1, b2, b3, b4, b0, b1, 11, 12)
    GSTEP(a3, a4, a0, a1, a2, b3, b4, b0, b1, b2, 12, 12)
    GSTEP(a4, a0, a1, a2, a3, b4, b0, b1, b2, b3, 13, 12)
    GSTEP(a0, a1, a2, a3, a4, b0, b1, b2, b3, b4, 14, 12)
    GSTEP(a1, a2, a3, a4, a0, b1, b2, b3, b4, b0, 15, 12)
    GSTEP(a2, a3, a4, a0, a1, b2, b3, b4, b0, b1, 16, 12)
    GSTEP(a3, a4, a0, a1, a2, b3, b4, b0, b1, b2, 17, 12)
    GSTEP(a4, a0, a1, a2, a3, b4, b0, b1, b2, b3, 18, 12)
    GSTEP(a0, a1, a2, a3, a4, b0, b1, b2, b3, b4, 19, 12)
    GSTEP(a1, a2, a3, a4, a0, b1, b2, b3, b4, b0, 20, 12)
    GSTEP(a2, a3, a4, a0, a1, b2, b3, b4, b0, b1, 21, 12)
    GSTEP(a3, a4, a0, a1, a2, b3, b4, b0, b1, b2, 22, 12)
    GSTEP(a4, a0, a1, a2, a3, b4, b0, b1, b2, b3, 23, 12)
    GSTEP(a0, a1, a2, a3, a4, b0, b1, b2, b3, b4, 24, 12)
    GSTEP(a1, a2, a3, a4, a0, b1, b2, b3, b4, b0, 25, 12)
    GSTEP(a2, a3, a4, a0, a1, b2, b3, b4, b0, b1, 26, 12)
    GSTEP(a3, a4, a0, a1, a2, b3, b4, b0, b1, b2, 27, 12)
    GSTEP(a4, a0, a1, a2, a3, b4, b0, b1, b2, b3, 28, 12)
    GSTEP(a0, a1, a2, a3, a4, b0, b1, b2, b3, b4, 29, 12)
    GSTEP(a1, a2, a3, a4, a0, b1, b2, b3, b4, b0, 30, 12)
    GSTEP(a2, a3, a4, a0, a1, b2, b3, b4, b0, b1, 31, 12)
    GSTEP(a3, a4, a0, a1, a2, b3, b4, b0, b1, b2, 32, 12)
    GSTEP(a4, a0, a1, a2, a3, b4, b0, b1, b2, b3, 33, 12)
    GSTEP(a0, a1, a2, a3, a4, b0, b1, b2, b3, b4, 34, 12)
    GSTEP(a1, a2, a3, a4, a0, b1, b2, b3, b4, b0, 35, 12)
#undef GSTEP
#undef STAGE
}

extern "C" void kernel_launch(void* const* d_in, const int* in_sizes, int n_in,
                              void* d_out, int out_size, void* d_ws, size_t ws_size,
                              hipStream_t stream)
{
    const float* x = (const float*)d_in[0];   // 2*16*64*128*128 fp32
    const float* w = (const float*)d_in[1];   // 16*1*5*5*5 fp32
    float*       o = (float*)d_out;

    dim3 grid(HH / 16, 2 * NC, DD / ZCHUNK);  // (8, 32, 2) = 512 blocks
    gauss3d_kernel<<<grid, 256, 0, stream>>>(x, w, o);
}